// Round 16
// baseline (197.961 us; speedup 1.0000x reference)
//
#include <hip/hip_runtime.h>

#define N_NODES 40000
#define N_EDGES 640000
#define IN_DIM 256
#define HID 128
#define NBUCK 313   // ceil(40000/128)
#define NCB 157     // count/scatter blocks (4096 edges each)
#define NCBP 160    // pbcnt row stride (ints, int4-aligned)

typedef short bf16x8 __attribute__((ext_vector_type(8)));
typedef float f32x4 __attribute__((ext_vector_type(4)));

__device__ __forceinline__ unsigned short f2bf(float f) {
    unsigned int u = __float_as_uint(f);
    unsigned int r = (u + 0x7FFFu + ((u >> 16) & 1u)) >> 16;
    return (unsigned short)r;
}
__device__ __forceinline__ float bf2f(unsigned short b) {
    return __uint_as_float(((unsigned int)b) << 16);
}

// ---------------- K1: per-block bucket hist (blocks 0..156) || W prep (blocks 157..604) ----------------
// pbcnt TRANSPOSED: pbcnt[bucket * NCBP + block].

__global__ __launch_bounds__(256) void count_prep(
    const int* __restrict__ dst, int* __restrict__ pbcnt, int E,
    const float* __restrict__ W0, const float* __restrict__ W1,
    const float* __restrict__ W2, const float* __restrict__ W3,
    unsigned short* __restrict__ H0, unsigned short* __restrict__ L0,
    unsigned short* __restrict__ H1, unsigned short* __restrict__ L1,
    unsigned short* __restrict__ H2, unsigned short* __restrict__ L2,
    unsigned short* __restrict__ H3, unsigned short* __restrict__ L3) {
    int bid = blockIdx.x, tid = threadIdx.x;
    if (bid < NCB) {
        __shared__ int cnt[NBUCK];
        for (int j = tid; j < NBUCK; j += 256) cnt[j] = 0;
        __syncthreads();
        int base = bid * 4096;
        int lim = min(base + 4096, E);
        for (int i = base + tid; i < lim; i += 256) atomicAdd(&cnt[dst[i] >> 7], 1);
        __syncthreads();
        for (int j = tid; j < NBUCK; j += 256) pbcnt[j * NCBP + bid] = cnt[j];
        return;
    }
    int i = (bid - NCB) * 256 + tid;
    const float* W;
    unsigned short *H, *L;
    int local;
    if (i < 32768)       { W = W0; H = H0; L = L0; local = i; }
    else if (i < 65536)  { W = W1; H = H1; L = L1; local = i - 32768; }
    else if (i < 98304)  { W = W2; H = H2; L = L2; local = i - 65536; }
    else if (i < 114688) { W = W3; H = H3; L = L3; local = i - 98304; }
    else return;
    int k = local >> 7, c = local & 127;
    float w = W[local];
    unsigned short h = f2bf(w);
    unsigned short l = f2bf(w - bf2f(h));
    int d = (k >> 5) * 4096 + c * 32 + (k & 31);
    H[d] = h;
    L[d] = l;
}

// ---------------- K2: gemm1 (blocks 0..624) || bucket scatter (625..781) ----------------
// gemm1: stage the block's CONTIGUOUS 64KB x-panel once (streaming read), convert to
// hi/lo bf16 in k-step-tiled LDS, then 8 k-steps read A from LDS only.
// smem aliased: gemm uses 80KB; scatter uses first 5KB.

__global__ __launch_bounds__(256) void scatter_gemm1(
    const int* __restrict__ src, const int* __restrict__ dst,
    const int* __restrict__ pbcnt, int* __restrict__ bbase, int* __restrict__ row_off,
    unsigned int* __restrict__ stage, int E,
    const float* __restrict__ x,
    const unsigned short* __restrict__ Bth, const unsigned short* __restrict__ Btl,
    const float* __restrict__ bias, unsigned short* __restrict__ Cbf) {
    __shared__ __align__(16) char smem[81920];
    int bid = blockIdx.x;
    int tid = threadIdx.x;
    if (bid >= 625) {
        int* sA = (int*)smem;          // 320
        int* sB = sA + 320;
        int* par = sB + 320;
        int* cnt = par + 320;
        int b2 = bid - 625;
#pragma unroll
        for (int jj = 0; jj < 2; ++jj) {
            int j = tid + jj * 256;
            if (j < 320) {
                int t = 0, p = 0;
                if (j < NBUCK) {
                    const int* row = &pbcnt[j * NCBP];
#pragma unroll 4
                    for (int g = 0; g < 39; ++g) {
                        int4 v = *(const int4*)&row[g * 4];
                        int blk0 = g * 4;
                        t += v.x + v.y + v.z + v.w;
                        if (blk0 + 0 < b2) p += v.x;
                        if (blk0 + 1 < b2) p += v.y;
                        if (blk0 + 2 < b2) p += v.z;
                        if (blk0 + 3 < b2) p += v.w;
                    }
                    int v156 = row[156];
                    t += v156;
                    if (156 < b2) p += v156;
                }
                sA[j] = t;
                par[j] = p;
            }
        }
        __syncthreads();
        int* bufs[2] = { sA, sB };
        int pp = 0;
#pragma unroll
        for (int off = 1; off < 512; off <<= 1) {
            int* sp = bufs[pp];
            int* dp = bufs[pp ^ 1];
#pragma unroll
            for (int jj = 0; jj < 2; ++jj) {
                int j = tid + jj * 256;
                if (j < 320) dp[j] = sp[j] + ((j >= off) ? sp[j - off] : 0);
            }
            pp ^= 1;
            __syncthreads();
        }
        int* incl = bufs[pp];
#pragma unroll
        for (int jj = 0; jj < 2; ++jj) {
            int j = tid + jj * 256;
            if (j < NBUCK) {
                int bb = (j > 0) ? incl[j - 1] : 0;
                cnt[j] = bb + par[j];
                if (b2 == 0) bbase[j] = bb;
            }
        }
        if (b2 == 0 && tid == 0) {
            bbase[NBUCK] = N_EDGES;
            row_off[N_NODES] = N_EDGES;
        }
        __syncthreads();
        int base = b2 * 4096;
        int lim = min(base + 4096, E);
        for (int i = base + tid; i < lim; i += 256) {
            unsigned int d = (unsigned int)dst[i];
            int p = atomicAdd(&cnt[d >> 7], 1);
            stage[p] = (d << 16) | (unsigned int)src[i];
        }
        return;
    }
    unsigned short* AhAll = (unsigned short*)smem;            // 8*64*32 = 32KB
    unsigned short* AlAll = (unsigned short*)(smem + 32768);  // 32KB
    unsigned short* Bh    = (unsigned short*)(smem + 65536);  // 8KB
    unsigned short* Bl    = (unsigned short*)(smem + 73728);  // 8KB
    int lane = tid & 63, wid = tid >> 6;
    int wr = wid >> 1, wc = wid & 1;
    int row0 = bid * 64;

    // stage full A panel: contiguous 64KB stream, 16 float4/thread
    {
        const float4* xb = (const float4*)&x[(size_t)row0 * IN_DIM];
#pragma unroll
        for (int p = 0; p < 16; ++p) {
            int idx = tid + p * 256;      // 0..4095
            float4 v = xb[idx];
            int r = idx >> 6;             // 64 float4 per row
            int c = (idx & 63) * 4;       // f32 col 0..252
            ushort4 hh, ll;
            hh.x = f2bf(v.x); ll.x = f2bf(v.x - bf2f(hh.x));
            hh.y = f2bf(v.y); ll.y = f2bf(v.y - bf2f(hh.y));
            hh.z = f2bf(v.z); ll.z = f2bf(v.z - bf2f(hh.z));
            hh.w = f2bf(v.w); ll.w = f2bf(v.w - bf2f(hh.w));
            int d = (c >> 5) * 2048 + r * 32 + (c & 31);
            *(ushort4*)&AhAll[d] = hh;
            *(ushort4*)&AlAll[d] = ll;
        }
    }
    __syncthreads();

    f32x4 acc[2][4];
#pragma unroll
    for (int rt = 0; rt < 2; ++rt)
#pragma unroll
        for (int ct = 0; ct < 4; ++ct) acc[rt][ct] = 0.f;

    for (int s = 0; s < 8; ++s) {
        {
            const float4* sh4 = (const float4*)(Bth + s * 4096);
            const float4* sl4 = (const float4*)(Btl + s * 4096);
            float4* dh4 = (float4*)Bh;
            float4* dl4 = (float4*)Bl;
            dh4[tid] = sh4[tid];
            dh4[tid + 256] = sh4[tid + 256];
            dl4[tid] = sl4[tid];
            dl4[tid + 256] = sl4[tid + 256];
        }
        __syncthreads();

        bf16x8 afh[2], afl[2], bfh[4], bfl[4];
#pragma unroll
        for (int rt = 0; rt < 2; ++rt) {
            int off = s * 2048 + (wr * 32 + rt * 16 + (lane & 15)) * 32 + (lane >> 4) * 8;
            afh[rt] = *(const bf16x8*)&AhAll[off];
            afl[rt] = *(const bf16x8*)&AlAll[off];
        }
#pragma unroll
        for (int ct = 0; ct < 4; ++ct) {
            int off = (wc * 64 + ct * 16 + (lane & 15)) * 32 + (lane >> 4) * 8;
            bfh[ct] = *(const bf16x8*)&Bh[off];
            bfl[ct] = *(const bf16x8*)&Bl[off];
        }
#pragma unroll
        for (int rt = 0; rt < 2; ++rt)
#pragma unroll
            for (int ct = 0; ct < 4; ++ct) {
                acc[rt][ct] = __builtin_amdgcn_mfma_f32_16x16x32_bf16(afh[rt], bfh[ct], acc[rt][ct], 0, 0, 0);
                acc[rt][ct] = __builtin_amdgcn_mfma_f32_16x16x32_bf16(afh[rt], bfl[ct], acc[rt][ct], 0, 0, 0);
                acc[rt][ct] = __builtin_amdgcn_mfma_f32_16x16x32_bf16(afl[rt], bfh[ct], acc[rt][ct], 0, 0, 0);
            }
        __syncthreads();
    }

#pragma unroll
    for (int ct = 0; ct < 4; ++ct) {
        int col = wc * 64 + ct * 16 + (lane & 15);
        float bv = bias[col];
#pragma unroll
        for (int rt = 0; rt < 2; ++rt) {
#pragma unroll
            for (int r = 0; r < 4; ++r) {
                int row = row0 + wr * 32 + rt * 16 + (lane >> 4) * 4 + r;
                float v = fmaxf(acc[rt][ct][r] + bv, 0.f);
                Cbf[(size_t)row * 128 + col] = f2bf(v);
            }
        }
    }
}

// ---------------- K3: per-bucket finalize -> row_off + csr ----------------

__global__ __launch_bounds__(256) void finalize_csr(const unsigned int* __restrict__ stage,
                                                    const int* __restrict__ bbase,
                                                    int* __restrict__ row_off,
                                                    int* __restrict__ csr) {
    __shared__ int ncnt[128];
    __shared__ int s2[128];
    int b = blockIdx.x, tid = threadIdx.x;
    int nbase = b << 7;
    int ncount = min(128, N_NODES - nbase);
    int ebase = bbase[b], eend = bbase[b + 1];
    if (tid < 128) ncnt[tid] = 0;
    __syncthreads();
    for (int i = ebase + tid; i < eend; i += 256)
        atomicAdd(&ncnt[(stage[i] >> 16) & 127], 1);
    __syncthreads();
    if (tid < 128) s2[tid] = ncnt[tid];
    __syncthreads();
#pragma unroll
    for (int off = 1; off < 128; off <<= 1) {
        int t = (tid < 128 && tid >= off) ? s2[tid - off] : 0;
        __syncthreads();
        if (tid < 128) s2[tid] += t;
        __syncthreads();
    }
    if (tid < 128) {
        int excl = s2[tid] - ncnt[tid];
        if (tid < ncount) row_off[nbase + tid] = ebase + excl;
        ncnt[tid] = excl;  // becomes local cursor
    }
    __syncthreads();
    for (int i = ebase + tid; i < eend; i += 256) {
        unsigned int ent = stage[i];
        int loc = (ent >> 16) & 127;
        int p = atomicAdd(&ncnt[loc], 1);
        csr[ebase + p] = (int)(ent & 0xFFFFu);
    }
}

// ---------------- mean aggregation (bf16 gather, fp32 accumulate, bf16 out) ----------------

__global__ __launch_bounds__(256) void agg_mean_bf(const unsigned short* __restrict__ hbf,
                                                   const int* __restrict__ row_off,
                                                   const int* __restrict__ csr,
                                                   unsigned short* __restrict__ out_bf,
                                                   int N) {
    int node = blockIdx.x * 4 + (threadIdx.x >> 6);
    if (node >= N) return;
    int lane = threadIdx.x & 63;
    int half = lane >> 5;
    int sub = lane & 31;
    int beg = row_off[node], end = row_off[node + 1];
    float4 a0 = make_float4(0.f, 0.f, 0.f, 0.f);
    float4 a1 = make_float4(0.f, 0.f, 0.f, 0.f);
    int e = beg;
    for (; e + 7 < end; e += 8) {
        int s0 = csr[e + half];
        int s1 = csr[e + 2 + half];
        int s2 = csr[e + 4 + half];
        int s3 = csr[e + 6 + half];
        ushort4 u0 = *(const ushort4*)&hbf[(size_t)s0 * HID + sub * 4];
        ushort4 u1 = *(const ushort4*)&hbf[(size_t)s1 * HID + sub * 4];
        ushort4 u2 = *(const ushort4*)&hbf[(size_t)s2 * HID + sub * 4];
        ushort4 u3 = *(const ushort4*)&hbf[(size_t)s3 * HID + sub * 4];
        a0.x += bf2f(u0.x) + bf2f(u2.x);
        a0.y += bf2f(u0.y) + bf2f(u2.y);
        a0.z += bf2f(u0.z) + bf2f(u2.z);
        a0.w += bf2f(u0.w) + bf2f(u2.w);
        a1.x += bf2f(u1.x) + bf2f(u3.x);
        a1.y += bf2f(u1.y) + bf2f(u3.y);
        a1.z += bf2f(u1.z) + bf2f(u3.z);
        a1.w += bf2f(u1.w) + bf2f(u3.w);
    }
    for (; e + half < end; e += 2) {
        int s = csr[e + half];
        ushort4 u = *(const ushort4*)&hbf[(size_t)s * HID + sub * 4];
        a0.x += bf2f(u.x);
        a0.y += bf2f(u.y);
        a0.z += bf2f(u.z);
        a0.w += bf2f(u.w);
    }
    float4 acc;
    acc.x = a0.x + a1.x;
    acc.y = a0.y + a1.y;
    acc.z = a0.z + a1.z;
    acc.w = a0.w + a1.w;
    acc.x += __shfl_xor(acc.x, 32);
    acc.y += __shfl_xor(acc.y, 32);
    acc.z += __shfl_xor(acc.z, 32);
    acc.w += __shfl_xor(acc.w, 32);
    if (half == 0) {
        float inv = 1.0f / fmaxf((float)(end - beg), 1.0f);
        ushort4 ub;
        ub.x = f2bf(acc.x * inv);
        ub.y = f2bf(acc.y * inv);
        ub.z = f2bf(acc.z * inv);
        ub.w = f2bf(acc.w * inv);
        *(ushort4*)&out_bf[(size_t)node * HID + sub * 4] = ub;
    }
}

// ---------------- bf16-A MFMA GEMM (mix0): full-A-panel staged ----------------

template <bool RELU>
__global__ __launch_bounds__(256) void gemm_a16(
    const unsigned short* __restrict__ A0, const unsigned short* __restrict__ A1,
    const unsigned short* __restrict__ Bth, const unsigned short* __restrict__ Btl,
    const float* __restrict__ bias, unsigned short* __restrict__ Cbf) {
    __shared__ unsigned short AbAll[8 * 64 * 32];  // 32KB
    __shared__ unsigned short Bh[128 * 32], Bl[128 * 32];
    int tid = threadIdx.x;
    int lane = tid & 63, wid = tid >> 6;
    int wr = wid >> 1, wc = wid & 1;
    int row0 = blockIdx.x * 64;

    // stage both A panels (contiguous 16KB each)
#pragma unroll
    for (int hf = 0; hf < 2; ++hf) {
        const unsigned short* Asrc = hf ? A1 : A0;
        const float4* ab = (const float4*)&Asrc[(size_t)row0 * HID];
#pragma unroll
        for (int p = 0; p < 4; ++p) {
            int idx = tid + p * 256;   // 0..1023
            float4 v = ab[idx];
            int r = idx >> 4;          // 16 chunks per row
            int c = (idx & 15) * 8;    // bf16 col
            int d = ((c >> 5) + hf * 4) * 2048 + r * 32 + (c & 31);
            *(float4*)&AbAll[d] = v;
        }
    }
    __syncthreads();

    f32x4 acc[2][4];
#pragma unroll
    for (int rt = 0; rt < 2; ++rt)
#pragma unroll
        for (int ct = 0; ct < 4; ++ct) acc[rt][ct] = 0.f;

    for (int s = 0; s < 8; ++s) {
        {
            const float4* sh4 = (const float4*)(Bth + s * 4096);
            const float4* sl4 = (const float4*)(Btl + s * 4096);
            float4* dh4 = (float4*)Bh;
            float4* dl4 = (float4*)Bl;
            dh4[tid] = sh4[tid];
            dh4[tid + 256] = sh4[tid + 256];
            dl4[tid] = sl4[tid];
            dl4[tid + 256] = sl4[tid + 256];
        }
        __syncthreads();

        bf16x8 af[2], bfh[4], bfl[4];
#pragma unroll
        for (int rt = 0; rt < 2; ++rt) {
            int off = s * 2048 + (wr * 32 + rt * 16 + (lane & 15)) * 32 + (lane >> 4) * 8;
            af[rt] = *(const bf16x8*)&AbAll[off];
        }
#pragma unroll
        for (int ct = 0; ct < 4; ++ct) {
            int off = (wc * 64 + ct * 16 + (lane & 15)) * 32 + (lane >> 4) * 8;
            bfh[ct] = *(const bf16x8*)&Bh[off];
            bfl[ct] = *(const bf16x8*)&Bl[off];
        }
#pragma unroll
        for (int rt = 0; rt < 2; ++rt)
#pragma unroll
            for (int ct = 0; ct < 4; ++ct) {
                acc[rt][ct] = __builtin_amdgcn_mfma_f32_16x16x32_bf16(af[rt], bfh[ct], acc[rt][ct], 0, 0, 0);
                acc[rt][ct] = __builtin_amdgcn_mfma_f32_16x16x32_bf16(af[rt], bfl[ct], acc[rt][ct], 0, 0, 0);
            }
        __syncthreads();
    }

#pragma unroll
    for (int ct = 0; ct < 4; ++ct) {
        int col = wc * 64 + ct * 16 + (lane & 15);
        float bv = bias[col];
#pragma unroll
        for (int rt = 0; rt < 2; ++rt) {
#pragma unroll
            for (int r = 0; r < 4; ++r) {
                int row = row0 + wr * 32 + rt * 16 + (lane >> 4) * 4 + r;
                float v = acc[rt][ct][r] + bv;
                if (RELU) v = fmaxf(v, 0.f);
                Cbf[(size_t)row * 128 + col] = f2bf(v);
            }
        }
    }
}

// ---------------- fused mix1 + out GEMM (full-A-panel staged) ----------------

__global__ __launch_bounds__(256) void gemm_mix_out(
    const unsigned short* __restrict__ A0, const unsigned short* __restrict__ A1,
    const unsigned short* __restrict__ BmH, const unsigned short* __restrict__ BmL,
    const float* __restrict__ bias_m,
    const unsigned short* __restrict__ BoH, const unsigned short* __restrict__ BoL,
    const float* __restrict__ bias_o, float* __restrict__ out) {
    __shared__ unsigned short AbAll[8 * 64 * 32];  // 32KB
    __shared__ unsigned short Bh[128 * 32], Bl[128 * 32];
    __shared__ unsigned short AoH[4][64 * 32], AoL[4][64 * 32];  // 32KB
    int tid = threadIdx.x;
    int lane = tid & 63, wid = tid >> 6;
    int wr = wid >> 1, wc = wid & 1;
    int row0 = blockIdx.x * 64;

#pragma unroll
    for (int hf = 0; hf < 2; ++hf) {
        const unsigned short* Asrc = hf ? A1 : A0;
        const float4* ab = (const float4*)&Asrc[(size_t)row0 * HID];
#pragma unroll
        for (int p = 0; p < 4; ++p) {
            int idx = tid + p * 256;
            float4 v = ab[idx];
            int r = idx >> 4;
            int c = (idx & 15) * 8;
            int d = ((c >> 5) + hf * 4) * 2048 + r * 32 + (c & 31);
            *(float4*)&AbAll[d] = v;
        }
    }
    __syncthreads();

    f32x4 acc[2][4];
#pragma unroll
    for (int rt = 0; rt < 2; ++rt)
#pragma unroll
        for (int ct = 0; ct < 4; ++ct) acc[rt][ct] = 0.f;

    // ---- phase 1: mix1 ----
    for (int s = 0; s < 8; ++s) {
        {
            const float4* sh4 = (const float4*)(BmH + s * 4096);
            const float4* sl4 = (const float4*)(BmL + s * 4096);
            float4* dh4 = (float4*)Bh;
            float4* dl4 = (float4*)Bl;
            dh4[tid] = sh4[tid];
            dh4[tid + 256] = sh4[tid + 256];
            dl4[tid] = sl4[tid];
            dl4[tid + 256] = sl4[tid + 256];
        }
        __syncthreads();

        bf16x8 af[2], bfh[4], bfl[4];
#pragma unroll
        for (int rt = 0; rt < 2; ++rt) {
            int off = s * 2048 + (wr * 32 + rt * 16 + (lane & 15)) * 32 + (lane >> 4) * 8;
            af[rt] = *(const bf16x8*)&AbAll[off];
        }
#pragma unroll
        for (int ct = 0; ct < 4; ++ct) {
            int off = (wc * 64 + ct * 16 + (lane & 15)) * 32 + (lane >> 4) * 8;
            bfh[ct] = *(const bf16x8*)&Bh[off];
            bfl[ct] = *(const bf16x8*)&Bl[off];
        }
#pragma unroll
        for (int rt = 0; rt < 2; ++rt)
#pragma unroll
            for (int ct = 0; ct < 4; ++ct) {
                acc[rt][ct] = __builtin_amdgcn_mfma_f32_16x16x32_bf16(af[rt], bfh[ct], acc[rt][ct], 0, 0, 0);
                acc[rt][ct] = __builtin_amdgcn_mfma_f32_16x16x32_bf16(af[rt], bfl[ct], acc[rt][ct], 0, 0, 0);
            }
        __syncthreads();
    }

    // ---- hand-off: mix1 tile -> hi/lo planes in LDS ----
#pragma unroll
    for (int ct = 0; ct < 4; ++ct) {
        int c = wc * 64 + ct * 16 + (lane & 15);
        int sp = c >> 5, cc = c & 31;
        float bv = bias_m[c];
#pragma unroll
        for (int rt = 0; rt < 2; ++rt) {
#pragma unroll
            for (int r = 0; r < 4; ++r) {
                int rl = wr * 32 + rt * 16 + (lane >> 4) * 4 + r;
                float v = acc[rt][ct][r] + bv;
                unsigned short h = f2bf(v);
                unsigned short l = f2bf(v - bf2f(h));
                AoH[sp][rl * 32 + cc] = h;
                AoL[sp][rl * 32 + cc] = l;
            }
        }
    }

#pragma unroll
    for (int rt = 0; rt < 2; ++rt)
#pragma unroll
        for (int ct = 0; ct < 4; ++ct) acc[rt][ct] = 0.f;

    // ---- phase 2: out = mix1 @ W_out + b_o ----
    for (int s = 0; s < 4; ++s) {
        {
            const float4* sh4 = (const float4*)(BoH + s * 4096);
            const float4* sl4 = (const float4*)(BoL + s * 4096);
            float4* dh4 = (float4*)Bh;
            float4* dl4 = (float4*)Bl;
            dh4[tid] = sh4[tid];
            dh4[tid + 256] = sh4[tid + 256];
            dl4[tid] = sl4[tid];
            dl4[tid + 256] = sl4[tid + 256];
        }
        __syncthreads();

        bf16x8 afh[2], afl[2], bfh[4], bfl[4];
#pragma unroll
        for (int rt = 0; rt < 2; ++rt) {
            int off = (wr * 32 + rt * 16 + (lane & 15)) * 32 + (lane >> 4) * 8;
            afh[rt] = *(const bf16x8*)&AoH[s][off];
            afl[rt] = *(const bf16x8*)&AoL[s][off];
        }
#pragma unroll
        for (int ct = 0; ct < 4; ++ct) {
            int off = (wc * 64 + ct * 16 + (lane & 15)) * 32 + (lane >> 4) * 8;
            bfh[ct] = *(const bf16x8*)&Bh[off];
            bfl[ct] = *(const bf16x8*)&Bl[off];
        }
#pragma unroll
        for (int rt = 0; rt < 2; ++rt)
#pragma unroll
            for (int ct = 0; ct < 4; ++ct) {
                acc[rt][ct] = __builtin_amdgcn_mfma_f32_16x16x32_bf16(afh[rt], bfh[ct], acc[rt][ct], 0, 0, 0);
                acc[rt][ct] = __builtin_amdgcn_mfma_f32_16x16x32_bf16(afh[rt], bfl[ct], acc[rt][ct], 0, 0, 0);
                acc[rt][ct] = __builtin_amdgcn_mfma_f32_16x16x32_bf16(afl[rt], bfh[ct], acc[rt][ct], 0, 0, 0);
            }
        __syncthreads();
    }

#pragma unroll
    for (int ct = 0; ct < 4; ++ct) {
        int col = wc * 64 + ct * 16 + (lane & 15);
        float bv = bias_o[col];
#pragma unroll
        for (int rt = 0; rt < 2; ++rt) {
#pragma unroll
            for (int r = 0; r < 4; ++r) {
                int row = row0 + wr * 32 + rt * 16 + (lane >> 4) * 4 + r;
                out[(size_t)row * 128 + col] = acc[rt][ct][r] + bv;
            }
        }
    }
}

// ---------------- launch ----------------

extern "C" void kernel_launch(void* const* d_in, const int* in_sizes, int n_in,
                              void* d_out, int out_size, void* d_ws, size_t ws_size,
                              hipStream_t stream) {
    const float* x     = (const float*)d_in[0];
    const float* W_in  = (const float*)d_in[1];
    const float* b_in  = (const float*)d_in[2];
    const float* W_m0  = (const float*)d_in[3];
    const float* b_m0  = (const float*)d_in[4];
    const float* W_m1  = (const float*)d_in[5];
    const float* b_m1  = (const float*)d_in[6];
    const float* W_o   = (const float*)d_in[7];
    const float* b_o   = (const float*)d_in[8];
    const int*   eidx  = (const int*)d_in[9];
    const int* src = eidx;
    const int* dst = eidx + N_EDGES;

    char* ws = (char*)d_ws;
    size_t off = 0;
    auto alloc = [&](size_t bytes) -> char* {
        char* p = ws + off;
        off += (bytes + 255) & ~(size_t)255;
        return p;
    };
    int* pbcnt   = (int*)alloc((size_t)NBUCK * NCBP * 4);
    int* bbase   = (int*)alloc((size_t)(NBUCK + 1) * 4);
    int* row_off = (int*)alloc((size_t)(N_NODES + 1) * 4);
    int* csr     = (int*)alloc((size_t)N_EDGES * 4);
    unsigned int* stage = (unsigned int*)alloc((size_t)N_EDGES * 4);
    unsigned short* hbf1 = (unsigned short*)alloc((size_t)N_NODES * HID * 2);
    unsigned short* hbf2 = (unsigned short*)alloc((size_t)N_NODES * HID * 2);
    unsigned short* hbf3 = (unsigned short*)alloc((size_t)N_NODES * HID * 2);
    unsigned short* WinH = (unsigned short*)alloc(32768 * 2);
    unsigned short* WinL = (unsigned short*)alloc(32768 * 2);
    unsigned short* Wm0H = (unsigned short*)alloc(32768 * 2);
    unsigned short* Wm0L = (unsigned short*)alloc(32768 * 2);
    unsigned short* Wm1H = (unsigned short*)alloc(32768 * 2);
    unsigned short* Wm1L = (unsigned short*)alloc(32768 * 2);
    unsigned short* WoH  = (unsigned short*)alloc(16384 * 2);
    unsigned short* WoL  = (unsigned short*)alloc(16384 * 2);
    (void)ws_size;

    count_prep<<<NCB + 448, 256, 0, stream>>>(dst, pbcnt, N_EDGES,
                                              W_in, W_m0, W_m1, W_o,
                                              WinH, WinL, Wm0H, Wm0L,
                                              Wm1H, Wm1L, WoH, WoL);
    scatter_gemm1<<<625 + NCB, 256, 0, stream>>>(src, dst, pbcnt, bbase, row_off,
                                                 stage, N_EDGES,
                                                 x, WinH, WinL, b_in, hbf1);
    finalize_csr<<<NBUCK, 256, 0, stream>>>(stage, bbase, row_off, csr);

    // layer 0
    agg_mean_bf<<<10000, 256, 0, stream>>>(hbf1, row_off, csr, hbf2, N_NODES);
    agg_mean_bf<<<10000, 256, 0, stream>>>(hbf2, row_off, csr, hbf3, N_NODES);
    gemm_a16<true><<<625, 256, 0, stream>>>(hbf2, hbf3, Wm0H, Wm0L, b_m0, hbf1);

    // layer 1
    agg_mean_bf<<<10000, 256, 0, stream>>>(hbf1, row_off, csr, hbf2, N_NODES);
    agg_mean_bf<<<10000, 256, 0, stream>>>(hbf2, row_off, csr, hbf3, N_NODES);

    // fused: mix1 + out
    gemm_mix_out<<<625, 256, 0, stream>>>(hbf2, hbf3, Wm1H, Wm1L, b_m1,
                                          WoH, WoL, b_o, (float*)d_out);
}

// Round 17
// 181.411 us; speedup vs baseline: 1.0912x; 1.0912x over previous
//
#include <hip/hip_runtime.h>

#define N_NODES 40000
#define N_EDGES 640000
#define IN_DIM 256
#define HID 128
#define NBUCK 313   // ceil(40000/128)
#define NCB 157     // count/scatter blocks (4096 edges each)
#define NCBP 160    // pbcnt row stride (ints, int4-aligned)

typedef short bf16x8 __attribute__((ext_vector_type(8)));
typedef float f32x4 __attribute__((ext_vector_type(4)));

__device__ __forceinline__ unsigned short f2bf(float f) {
    unsigned int u = __float_as_uint(f);
    unsigned int r = (u + 0x7FFFu + ((u >> 16) & 1u)) >> 16;
    return (unsigned short)r;
}
__device__ __forceinline__ float bf2f(unsigned short b) {
    return __uint_as_float(((unsigned int)b) << 16);
}

// ---------------- K1: per-block bucket hist (blocks 0..156) || W prep (blocks 157..604) ----------------
// pbcnt TRANSPOSED: pbcnt[bucket * NCBP + block] -> scatter reads become contiguous int4.

__global__ __launch_bounds__(256) void count_prep(
    const int* __restrict__ dst, int* __restrict__ pbcnt, int E,
    const float* __restrict__ W0, const float* __restrict__ W1,
    const float* __restrict__ W2, const float* __restrict__ W3,
    unsigned short* __restrict__ H0, unsigned short* __restrict__ L0,
    unsigned short* __restrict__ H1, unsigned short* __restrict__ L1,
    unsigned short* __restrict__ H2, unsigned short* __restrict__ L2,
    unsigned short* __restrict__ H3, unsigned short* __restrict__ L3) {
    int bid = blockIdx.x, tid = threadIdx.x;
    if (bid < NCB) {
        __shared__ int cnt[NBUCK];
        for (int j = tid; j < NBUCK; j += 256) cnt[j] = 0;
        __syncthreads();
        int base = bid * 4096;
        int lim = min(base + 4096, E);
        for (int i = base + tid; i < lim; i += 256) atomicAdd(&cnt[dst[i] >> 7], 1);
        __syncthreads();
        for (int j = tid; j < NBUCK; j += 256) pbcnt[j * NCBP + bid] = cnt[j];
        return;
    }
    int i = (bid - NCB) * 256 + tid;
    const float* W;
    unsigned short *H, *L;
    int local;
    if (i < 32768)       { W = W0; H = H0; L = L0; local = i; }
    else if (i < 65536)  { W = W1; H = H1; L = L1; local = i - 32768; }
    else if (i < 98304)  { W = W2; H = H2; L = L2; local = i - 65536; }
    else if (i < 114688) { W = W3; H = H3; L = L3; local = i - 98304; }
    else return;
    int k = local >> 7, c = local & 127;
    float w = W[local];
    unsigned short h = f2bf(w);
    unsigned short l = f2bf(w - bf2f(h));
    int d = (k >> 5) * 4096 + c * 32 + (k & 31);
    H[d] = h;
    L[d] = l;
}

// ---------------- K2: gemm1 (blocks 0..624) || bucket scatter w/ parallel scan (625..781) ----------------

__global__ __launch_bounds__(256) void scatter_gemm1(
    const int* __restrict__ src, const int* __restrict__ dst,
    const int* __restrict__ pbcnt, int* __restrict__ bbase, int* __restrict__ row_off,
    unsigned int* __restrict__ stage, int E,
    const float* __restrict__ x,
    const unsigned short* __restrict__ Bth, const unsigned short* __restrict__ Btl,
    const float* __restrict__ bias, unsigned short* __restrict__ Cbf) {
    int bid = blockIdx.x;
    int tid = threadIdx.x;
    if (bid >= 625) {
        __shared__ int sA[320], sB[320], par[320], cnt[320];
        int b2 = bid - 625;
        // per-row contiguous sums: tot (all 157) and par (blocks < b2)
#pragma unroll
        for (int jj = 0; jj < 2; ++jj) {
            int j = tid + jj * 256;
            if (j < 320) {
                int t = 0, p = 0;
                if (j < NBUCK) {
                    const int* row = &pbcnt[j * NCBP];
#pragma unroll 4
                    for (int g = 0; g < 39; ++g) {
                        int4 v = *(const int4*)&row[g * 4];
                        int blk0 = g * 4;
                        t += v.x + v.y + v.z + v.w;
                        if (blk0 + 0 < b2) p += v.x;
                        if (blk0 + 1 < b2) p += v.y;
                        if (blk0 + 2 < b2) p += v.z;
                        if (blk0 + 3 < b2) p += v.w;
                    }
                    int v156 = row[156];
                    t += v156;
                    if (156 < b2) p += v156;
                }
                sA[j] = t;
                par[j] = p;
            }
        }
        __syncthreads();
        // Hillis-Steele inclusive scan over 320 slots (9 steps, ping-pong)
        int* bufs[2] = { sA, sB };
        int pp = 0;
#pragma unroll
        for (int off = 1; off < 512; off <<= 1) {
            int* sp = bufs[pp];
            int* dp = bufs[pp ^ 1];
#pragma unroll
            for (int jj = 0; jj < 2; ++jj) {
                int j = tid + jj * 256;
                if (j < 320) dp[j] = sp[j] + ((j >= off) ? sp[j - off] : 0);
            }
            pp ^= 1;
            __syncthreads();
        }
        int* incl = bufs[pp];
#pragma unroll
        for (int jj = 0; jj < 2; ++jj) {
            int j = tid + jj * 256;
            if (j < NBUCK) {
                int bb = (j > 0) ? incl[j - 1] : 0;
                cnt[j] = bb + par[j];
                if (b2 == 0) bbase[j] = bb;
            }
        }
        if (b2 == 0 && tid == 0) {
            bbase[NBUCK] = N_EDGES;
            row_off[N_NODES] = N_EDGES;
        }
        __syncthreads();
        int base = b2 * 4096;
        int lim = min(base + 4096, E);
        for (int i = base + tid; i < lim; i += 256) {
            unsigned int d = (unsigned int)dst[i];
            int p = atomicAdd(&cnt[d >> 7], 1);
            stage[p] = (d << 16) | (unsigned int)src[i];
        }
        return;
    }
    __shared__ unsigned short Ah[64 * 32], Al[64 * 32];
    __shared__ unsigned short Bh[128 * 32], Bl[128 * 32];
    int lane = tid & 63, wid = tid >> 6;
    int wr = wid >> 1, wc = wid & 1;
    int row0 = bid * 64;

    f32x4 acc[2][4];
#pragma unroll
    for (int rt = 0; rt < 2; ++rt)
#pragma unroll
        for (int ct = 0; ct < 4; ++ct) acc[rt][ct] = 0.f;

    for (int s = 0; s < 8; ++s) {
        int kbase = s * 32;
#pragma unroll
        for (int i = 0; i < 2; ++i) {
            int cch = tid + i * 256;
            int r = cch >> 3, q = cch & 7;
            float4 v = *(const float4*)&x[(size_t)(row0 + r) * IN_DIM + kbase + q * 4];
            ushort4 hh, ll;
            hh.x = f2bf(v.x); ll.x = f2bf(v.x - bf2f(hh.x));
            hh.y = f2bf(v.y); ll.y = f2bf(v.y - bf2f(hh.y));
            hh.z = f2bf(v.z); ll.z = f2bf(v.z - bf2f(hh.z));
            hh.w = f2bf(v.w); ll.w = f2bf(v.w - bf2f(hh.w));
            *(ushort4*)&Ah[r * 32 + q * 4] = hh;
            *(ushort4*)&Al[r * 32 + q * 4] = ll;
        }
        {
            const float4* sh4 = (const float4*)(Bth + s * 4096);
            const float4* sl4 = (const float4*)(Btl + s * 4096);
            float4* dh4 = (float4*)Bh;
            float4* dl4 = (float4*)Bl;
            dh4[tid] = sh4[tid];
            dh4[tid + 256] = sh4[tid + 256];
            dl4[tid] = sl4[tid];
            dl4[tid + 256] = sl4[tid + 256];
        }
        __syncthreads();

        bf16x8 afh[2], afl[2], bfh[4], bfl[4];
#pragma unroll
        for (int rt = 0; rt < 2; ++rt) {
            int off = (wr * 32 + rt * 16 + (lane & 15)) * 32 + (lane >> 4) * 8;
            afh[rt] = *(const bf16x8*)&Ah[off];
            afl[rt] = *(const bf16x8*)&Al[off];
        }
#pragma unroll
        for (int ct = 0; ct < 4; ++ct) {
            int off = (wc * 64 + ct * 16 + (lane & 15)) * 32 + (lane >> 4) * 8;
            bfh[ct] = *(const bf16x8*)&Bh[off];
            bfl[ct] = *(const bf16x8*)&Bl[off];
        }
#pragma unroll
        for (int rt = 0; rt < 2; ++rt)
#pragma unroll
            for (int ct = 0; ct < 4; ++ct) {
                acc[rt][ct] = __builtin_amdgcn_mfma_f32_16x16x32_bf16(afh[rt], bfh[ct], acc[rt][ct], 0, 0, 0);
                acc[rt][ct] = __builtin_amdgcn_mfma_f32_16x16x32_bf16(afh[rt], bfl[ct], acc[rt][ct], 0, 0, 0);
                acc[rt][ct] = __builtin_amdgcn_mfma_f32_16x16x32_bf16(afl[rt], bfh[ct], acc[rt][ct], 0, 0, 0);
            }
        __syncthreads();
    }

#pragma unroll
    for (int ct = 0; ct < 4; ++ct) {
        int col = wc * 64 + ct * 16 + (lane & 15);
        float bv = bias[col];
#pragma unroll
        for (int rt = 0; rt < 2; ++rt) {
#pragma unroll
            for (int r = 0; r < 4; ++r) {
                int row = row0 + wr * 32 + rt * 16 + (lane >> 4) * 4 + r;
                float v = fmaxf(acc[rt][ct][r] + bv, 0.f);
                Cbf[(size_t)row * 128 + col] = f2bf(v);
            }
        }
    }
}

// ---------------- K3: per-bucket finalize -> row_off + csr ----------------

__global__ __launch_bounds__(256) void finalize_csr(const unsigned int* __restrict__ stage,
                                                    const int* __restrict__ bbase,
                                                    int* __restrict__ row_off,
                                                    int* __restrict__ csr) {
    __shared__ int ncnt[128];
    __shared__ int s2[128];
    int b = blockIdx.x, tid = threadIdx.x;
    int nbase = b << 7;
    int ncount = min(128, N_NODES - nbase);
    int ebase = bbase[b], eend = bbase[b + 1];
    if (tid < 128) ncnt[tid] = 0;
    __syncthreads();
    for (int i = ebase + tid; i < eend; i += 256)
        atomicAdd(&ncnt[(stage[i] >> 16) & 127], 1);
    __syncthreads();
    if (tid < 128) s2[tid] = ncnt[tid];
    __syncthreads();
#pragma unroll
    for (int off = 1; off < 128; off <<= 1) {
        int t = (tid < 128 && tid >= off) ? s2[tid - off] : 0;
        __syncthreads();
        if (tid < 128) s2[tid] += t;
        __syncthreads();
    }
    if (tid < 128) {
        int excl = s2[tid] - ncnt[tid];
        if (tid < ncount) row_off[nbase + tid] = ebase + excl;
        ncnt[tid] = excl;  // becomes local cursor
    }
    __syncthreads();
    for (int i = ebase + tid; i < eend; i += 256) {
        unsigned int ent = stage[i];
        int loc = (ent >> 16) & 127;
        int p = atomicAdd(&ncnt[loc], 1);
        csr[ebase + p] = (int)(ent & 0xFFFFu);
    }
}

// ---------------- mean aggregation (bf16 gather, fp32 accumulate, bf16 out) ----------------

__global__ __launch_bounds__(256) void agg_mean_bf(const unsigned short* __restrict__ hbf,
                                                   const int* __restrict__ row_off,
                                                   const int* __restrict__ csr,
                                                   unsigned short* __restrict__ out_bf,
                                                   int N) {
    int node = blockIdx.x * 4 + (threadIdx.x >> 6);
    if (node >= N) return;
    int lane = threadIdx.x & 63;
    int half = lane >> 5;
    int sub = lane & 31;
    int beg = row_off[node], end = row_off[node + 1];
    float4 a0 = make_float4(0.f, 0.f, 0.f, 0.f);
    float4 a1 = make_float4(0.f, 0.f, 0.f, 0.f);
    int e = beg;
    for (; e + 7 < end; e += 8) {
        int s0 = csr[e + half];
        int s1 = csr[e + 2 + half];
        int s2 = csr[e + 4 + half];
        int s3 = csr[e + 6 + half];
        ushort4 u0 = *(const ushort4*)&hbf[(size_t)s0 * HID + sub * 4];
        ushort4 u1 = *(const ushort4*)&hbf[(size_t)s1 * HID + sub * 4];
        ushort4 u2 = *(const ushort4*)&hbf[(size_t)s2 * HID + sub * 4];
        ushort4 u3 = *(const ushort4*)&hbf[(size_t)s3 * HID + sub * 4];
        a0.x += bf2f(u0.x) + bf2f(u2.x);
        a0.y += bf2f(u0.y) + bf2f(u2.y);
        a0.z += bf2f(u0.z) + bf2f(u2.z);
        a0.w += bf2f(u0.w) + bf2f(u2.w);
        a1.x += bf2f(u1.x) + bf2f(u3.x);
        a1.y += bf2f(u1.y) + bf2f(u3.y);
        a1.z += bf2f(u1.z) + bf2f(u3.z);
        a1.w += bf2f(u1.w) + bf2f(u3.w);
    }
    for (; e + half < end; e += 2) {
        int s = csr[e + half];
        ushort4 u = *(const ushort4*)&hbf[(size_t)s * HID + sub * 4];
        a0.x += bf2f(u.x);
        a0.y += bf2f(u.y);
        a0.z += bf2f(u.z);
        a0.w += bf2f(u.w);
    }
    float4 acc;
    acc.x = a0.x + a1.x;
    acc.y = a0.y + a1.y;
    acc.z = a0.z + a1.z;
    acc.w = a0.w + a1.w;
    acc.x += __shfl_xor(acc.x, 32);
    acc.y += __shfl_xor(acc.y, 32);
    acc.z += __shfl_xor(acc.z, 32);
    acc.w += __shfl_xor(acc.w, 32);
    if (half == 0) {
        float inv = 1.0f / fmaxf((float)(end - beg), 1.0f);
        ushort4 ub;
        ub.x = f2bf(acc.x * inv);
        ub.y = f2bf(acc.y * inv);
        ub.z = f2bf(acc.z * inv);
        ub.w = f2bf(acc.w * inv);
        *(ushort4*)&out_bf[(size_t)node * HID + sub * 4] = ub;
    }
}

// ---------------- bf16-A MFMA GEMM (mix0): C = [A0|A1] @ W + b -> bf16 ----------------

template <bool RELU>
__global__ __launch_bounds__(256) void gemm_a16(
    const unsigned short* __restrict__ A0, const unsigned short* __restrict__ A1,
    const unsigned short* __restrict__ Bth, const unsigned short* __restrict__ Btl,
    const float* __restrict__ bias, unsigned short* __restrict__ Cbf) {
    __shared__ unsigned short Ab[64 * 32];
    __shared__ unsigned short Bh[128 * 32], Bl[128 * 32];
    int tid = threadIdx.x;
    int lane = tid & 63, wid = tid >> 6;
    int wr = wid >> 1, wc = wid & 1;
    int row0 = blockIdx.x * 64;

    f32x4 acc[2][4];
#pragma unroll
    for (int rt = 0; rt < 2; ++rt)
#pragma unroll
        for (int ct = 0; ct < 4; ++ct) acc[rt][ct] = 0.f;

    for (int s = 0; s < 8; ++s) {
        const unsigned short* Asrc = (s < 4) ? A0 : A1;
        int kbase = (s & 3) * 32;
        {
            int r = tid >> 2, q = (tid & 3) * 8;
            *(float4*)&Ab[r * 32 + q] =
                *(const float4*)&Asrc[(size_t)(row0 + r) * HID + kbase + q];
        }
        {
            const float4* sh4 = (const float4*)(Bth + s * 4096);
            const float4* sl4 = (const float4*)(Btl + s * 4096);
            float4* dh4 = (float4*)Bh;
            float4* dl4 = (float4*)Bl;
            dh4[tid] = sh4[tid];
            dh4[tid + 256] = sh4[tid + 256];
            dl4[tid] = sl4[tid];
            dl4[tid + 256] = sl4[tid + 256];
        }
        __syncthreads();

        bf16x8 af[2], bfh[4], bfl[4];
#pragma unroll
        for (int rt = 0; rt < 2; ++rt) {
            int off = (wr * 32 + rt * 16 + (lane & 15)) * 32 + (lane >> 4) * 8;
            af[rt] = *(const bf16x8*)&Ab[off];
        }
#pragma unroll
        for (int ct = 0; ct < 4; ++ct) {
            int off = (wc * 64 + ct * 16 + (lane & 15)) * 32 + (lane >> 4) * 8;
            bfh[ct] = *(const bf16x8*)&Bh[off];
            bfl[ct] = *(const bf16x8*)&Bl[off];
        }
#pragma unroll
        for (int rt = 0; rt < 2; ++rt)
#pragma unroll
            for (int ct = 0; ct < 4; ++ct) {
                acc[rt][ct] = __builtin_amdgcn_mfma_f32_16x16x32_bf16(af[rt], bfh[ct], acc[rt][ct], 0, 0, 0);
                acc[rt][ct] = __builtin_amdgcn_mfma_f32_16x16x32_bf16(af[rt], bfl[ct], acc[rt][ct], 0, 0, 0);
            }
        __syncthreads();
    }

#pragma unroll
    for (int ct = 0; ct < 4; ++ct) {
        int col = wc * 64 + ct * 16 + (lane & 15);
        float bv = bias[col];
#pragma unroll
        for (int rt = 0; rt < 2; ++rt) {
#pragma unroll
            for (int r = 0; r < 4; ++r) {
                int row = row0 + wr * 32 + rt * 16 + (lane >> 4) * 4 + r;
                float v = acc[rt][ct][r] + bv;
                if (RELU) v = fmaxf(v, 0.f);
                Cbf[(size_t)row * 128 + col] = f2bf(v);
            }
        }
    }
}

// ---------------- fused mix1 + out GEMM ----------------

__global__ __launch_bounds__(256) void gemm_mix_out(
    const unsigned short* __restrict__ A0, const unsigned short* __restrict__ A1,
    const unsigned short* __restrict__ BmH, const unsigned short* __restrict__ BmL,
    const float* __restrict__ bias_m,
    const unsigned short* __restrict__ BoH, const unsigned short* __restrict__ BoL,
    const float* __restrict__ bias_o, float* __restrict__ out) {
    __shared__ unsigned short Ab[64 * 32];
    __shared__ unsigned short Bh[128 * 32], Bl[128 * 32];
    __shared__ unsigned short AoH[4][64 * 32], AoL[4][64 * 32];
    int tid = threadIdx.x;
    int lane = tid & 63, wid = tid >> 6;
    int wr = wid >> 1, wc = wid & 1;
    int row0 = blockIdx.x * 64;

    f32x4 acc[2][4];
#pragma unroll
    for (int rt = 0; rt < 2; ++rt)
#pragma unroll
        for (int ct = 0; ct < 4; ++ct) acc[rt][ct] = 0.f;

    for (int s = 0; s < 8; ++s) {
        const unsigned short* Asrc = (s < 4) ? A0 : A1;
        int kbase = (s & 3) * 32;
        {
            int r = tid >> 2, q = (tid & 3) * 8;
            *(float4*)&Ab[r * 32 + q] =
                *(const float4*)&Asrc[(size_t)(row0 + r) * HID + kbase + q];
        }
        {
            const float4* sh4 = (const float4*)(BmH + s * 4096);
            const float4* sl4 = (const float4*)(BmL + s * 4096);
            float4* dh4 = (float4*)Bh;
            float4* dl4 = (float4*)Bl;
            dh4[tid] = sh4[tid];
            dh4[tid + 256] = sh4[tid + 256];
            dl4[tid] = sl4[tid];
            dl4[tid + 256] = sl4[tid + 256];
        }
        __syncthreads();

        bf16x8 af[2], bfh[4], bfl[4];
#pragma unroll
        for (int rt = 0; rt < 2; ++rt) {
            int off = (wr * 32 + rt * 16 + (lane & 15)) * 32 + (lane >> 4) * 8;
            af[rt] = *(const bf16x8*)&Ab[off];
        }
#pragma unroll
        for (int ct = 0; ct < 4; ++ct) {
            int off = (wc * 64 + ct * 16 + (lane & 15)) * 32 + (lane >> 4) * 8;
            bfh[ct] = *(const bf16x8*)&Bh[off];
            bfl[ct] = *(const bf16x8*)&Bl[off];
        }
#pragma unroll
        for (int rt = 0; rt < 2; ++rt)
#pragma unroll
            for (int ct = 0; ct < 4; ++ct) {
                acc[rt][ct] = __builtin_amdgcn_mfma_f32_16x16x32_bf16(af[rt], bfh[ct], acc[rt][ct], 0, 0, 0);
                acc[rt][ct] = __builtin_amdgcn_mfma_f32_16x16x32_bf16(af[rt], bfl[ct], acc[rt][ct], 0, 0, 0);
            }
        __syncthreads();
    }

#pragma unroll
    for (int ct = 0; ct < 4; ++ct) {
        int c = wc * 64 + ct * 16 + (lane & 15);
        int sp = c >> 5, cc = c & 31;
        float bv = bias_m[c];
#pragma unroll
        for (int rt = 0; rt < 2; ++rt) {
#pragma unroll
            for (int r = 0; r < 4; ++r) {
                int rl = wr * 32 + rt * 16 + (lane >> 4) * 4 + r;
                float v = acc[rt][ct][r] + bv;
                unsigned short h = f2bf(v);
                unsigned short l = f2bf(v - bf2f(h));
                AoH[sp][rl * 32 + cc] = h;
                AoL[sp][rl * 32 + cc] = l;
            }
        }
    }

#pragma unroll
    for (int rt = 0; rt < 2; ++rt)
#pragma unroll
        for (int ct = 0; ct < 4; ++ct) acc[rt][ct] = 0.f;

    for (int s = 0; s < 4; ++s) {
        {
            const float4* sh4 = (const float4*)(BoH + s * 4096);
            const float4* sl4 = (const float4*)(BoL + s * 4096);
            float4* dh4 = (float4*)Bh;
            float4* dl4 = (float4*)Bl;
            dh4[tid] = sh4[tid];
            dh4[tid + 256] = sh4[tid + 256];
            dl4[tid] = sl4[tid];
            dl4[tid + 256] = sl4[tid + 256];
        }
        __syncthreads();

        bf16x8 afh[2], afl[2], bfh[4], bfl[4];
#pragma unroll
        for (int rt = 0; rt < 2; ++rt) {
            int off = (wr * 32 + rt * 16 + (lane & 15)) * 32 + (lane >> 4) * 8;
            afh[rt] = *(const bf16x8*)&AoH[s][off];
            afl[rt] = *(const bf16x8*)&AoL[s][off];
        }
#pragma unroll
        for (int ct = 0; ct < 4; ++ct) {
            int off = (wc * 64 + ct * 16 + (lane & 15)) * 32 + (lane >> 4) * 8;
            bfh[ct] = *(const bf16x8*)&Bh[off];
            bfl[ct] = *(const bf16x8*)&Bl[off];
        }
#pragma unroll
        for (int rt = 0; rt < 2; ++rt)
#pragma unroll
            for (int ct = 0; ct < 4; ++ct) {
                acc[rt][ct] = __builtin_amdgcn_mfma_f32_16x16x32_bf16(afh[rt], bfh[ct], acc[rt][ct], 0, 0, 0);
                acc[rt][ct] = __builtin_amdgcn_mfma_f32_16x16x32_bf16(afh[rt], bfl[ct], acc[rt][ct], 0, 0, 0);
                acc[rt][ct] = __builtin_amdgcn_mfma_f32_16x16x32_bf16(afl[rt], bfh[ct], acc[rt][ct], 0, 0, 0);
            }
        __syncthreads();
    }

#pragma unroll
    for (int ct = 0; ct < 4; ++ct) {
        int col = wc * 64 + ct * 16 + (lane & 15);
        float bv = bias_o[col];
#pragma unroll
        for (int rt = 0; rt < 2; ++rt) {
#pragma unroll
            for (int r = 0; r < 4; ++r) {
                int row = row0 + wr * 32 + rt * 16 + (lane >> 4) * 4 + r;
                out[(size_t)row * 128 + col] = acc[rt][ct][r] + bv;
            }
        }
    }
}

// ---------------- launch ----------------

extern "C" void kernel_launch(void* const* d_in, const int* in_sizes, int n_in,
                              void* d_out, int out_size, void* d_ws, size_t ws_size,
                              hipStream_t stream) {
    const float* x     = (const float*)d_in[0];
    const float* W_in  = (const float*)d_in[1];
    const float* b_in  = (const float*)d_in[2];
    const float* W_m0  = (const float*)d_in[3];
    const float* b_m0  = (const float*)d_in[4];
    const float* W_m1  = (const float*)d_in[5];
    const float* b_m1  = (const float*)d_in[6];
    const float* W_o   = (const float*)d_in[7];
    const float* b_o   = (const float*)d_in[8];
    const int*   eidx  = (const int*)d_in[9];
    const int* src = eidx;
    const int* dst = eidx + N_EDGES;

    char* ws = (char*)d_ws;
    size_t off = 0;
    auto alloc = [&](size_t bytes) -> char* {
        char* p = ws + off;
        off += (bytes + 255) & ~(size_t)255;
        return p;
    };
    int* pbcnt   = (int*)alloc((size_t)NBUCK * NCBP * 4);
    int* bbase   = (int*)alloc((size_t)(NBUCK + 1) * 4);
    int* row_off = (int*)alloc((size_t)(N_NODES + 1) * 4);
    int* csr     = (int*)alloc((size_t)N_EDGES * 4);
    unsigned int* stage = (unsigned int*)alloc((size_t)N_EDGES * 4);
    unsigned short* hbf1 = (unsigned short*)alloc((size_t)N_NODES * HID * 2);
    unsigned short* hbf2 = (unsigned short*)alloc((size_t)N_NODES * HID * 2);
    unsigned short* hbf3 = (unsigned short*)alloc((size_t)N_NODES * HID * 2);
    unsigned short* WinH = (unsigned short*)alloc(32768 * 2);
    unsigned short* WinL = (unsigned short*)alloc(32768 * 2);
    unsigned short* Wm0H = (unsigned short*)alloc(32768 * 2);
    unsigned short* Wm0L = (unsigned short*)alloc(32768 * 2);
    unsigned short* Wm1H = (unsigned short*)alloc(32768 * 2);
    unsigned short* Wm1L = (unsigned short*)alloc(32768 * 2);
    unsigned short* WoH  = (unsigned short*)alloc(16384 * 2);
    unsigned short* WoL  = (unsigned short*)alloc(16384 * 2);
    (void)ws_size;

    count_prep<<<NCB + 448, 256, 0, stream>>>(dst, pbcnt, N_EDGES,
                                              W_in, W_m0, W_m1, W_o,
                                              WinH, WinL, Wm0H, Wm0L,
                                              Wm1H, Wm1L, WoH, WoL);
    scatter_gemm1<<<625 + NCB, 256, 0, stream>>>(src, dst, pbcnt, bbase, row_off,
                                                 stage, N_EDGES,
                                                 x, WinH, WinL, b_in, hbf1);
    finalize_csr<<<NBUCK, 256, 0, stream>>>(stage, bbase, row_off, csr);

    // layer 0
    agg_mean_bf<<<10000, 256, 0, stream>>>(hbf1, row_off, csr, hbf2, N_NODES);
    agg_mean_bf<<<10000, 256, 0, stream>>>(hbf2, row_off, csr, hbf3, N_NODES);
    gemm_a16<true><<<625, 256, 0, stream>>>(hbf2, hbf3, Wm0H, Wm0L, b_m0, hbf1);

    // layer 1
    agg_mean_bf<<<10000, 256, 0, stream>>>(hbf1, row_off, csr, hbf2, N_NODES);
    agg_mean_bf<<<10000, 256, 0, stream>>>(hbf2, row_off, csr, hbf3, N_NODES);

    // fused: mix1 + out
    gemm_mix_out<<<625, 256, 0, stream>>>(hbf2, hbf3, Wm1H, Wm1L, b_m1,
                                          WoH, WoL, b_o, (float*)d_out);
}